// Round 2
// 212.280 us; speedup vs baseline: 1.0061x; 1.0061x over previous
//
#include <hip/hip_runtime.h>

#define B 8
#define E 2000
#define NTRI 10000
#define NRELS 25
#define KT 16
#define TT 3
#define LL 32
#define TAU1 10.0f
#define XBLK 8192
#define XTHR 256
#define LCAP 256

typedef __attribute__((ext_vector_type(4))) float f32x4;

__device__ __forceinline__ float clip01(float x) { return fminf(fmaxf(x, 0.0f), 1.0f); }

// Kernel 1: one pass over all dense one-hot inputs. Every row/column involved
// is one-hot by construction, so each output slot has EXACTLY ONE writer:
// plain stores, no atomics, no memset node. The two 80 MB sweeps are
// INTERLEAVED (2 independent non-temporal 16B loads per iteration) so twice
// as many loads are in flight at the same occupancy.
// Also zeroes d_out/mask/cnt and precomputes all 96 softmax rows of w
// (previously each of 256 blocks recomputed its row serially, 3x).
__global__ void __launch_bounds__(XTHR) extract_all(
        const f32x4* __restrict__ e2t, const f32x4* __restrict__ t2e,
        const float4* __restrict__ t2r, const float4* __restrict__ ix,
        const float4* __restrict__ tm, const float* __restrict__ w,
        int* __restrict__ heads, int* __restrict__ tails, int* __restrict__ rels,
        int* __restrict__ ent, int* __restrict__ tidx,
        unsigned int* __restrict__ mask_g, int* __restrict__ cnt_g,
        float* __restrict__ wrow_g, float4* __restrict__ out4) {
    const int gtid = blockIdx.x * XTHR + threadIdx.x;
    const int gs = XBLK * XTHR;

    // zero aux state
    if (gtid < 2048) mask_g[gtid] = 0u;
    if (gtid < 64) cnt_g[gtid] = 0;
    float4 z = make_float4(0.f, 0.f, 0.f, 0.f);
    for (int i = gtid; i < B * E / 4; i += gs) out4[i] = z;

    // all 96 softmax rows of w, one thread each
    if (gtid < TT * LL) {
        const float* wr = w + gtid * NRELS;
        float mx = wr[0];
        for (int r = 1; r < NRELS; r++) mx = fmaxf(mx, wr[r]);
        float ex[NRELS], s = 0.f;
        for (int r = 0; r < NRELS; r++) { ex[r] = expf(wr[r] - mx); s += ex[r]; }
        float inv = 1.f / s;
        for (int r = 0; r < NRELS; r++) wrow_g[gtid * NRELS + r] = ex[r] * inv;
    }

    // input_x [B,E]: ent[b] = col  (4000 float4)
    for (int i = gtid; i < B * E / 4; i += gs) {
        float4 v = ix[i];
        if (v.x != 0.f || v.y != 0.f || v.z != 0.f || v.w != 0.f) {
            float c[4] = {v.x, v.y, v.z, v.w};
#pragma unroll
            for (int k = 0; k < 4; k++)
                if (c[k] != 0.f) { int a = i * 4 + k; int bq = a / E; ent[bq] = a - bq * E; }
        }
    }
    // type_mat [E,KT]: tidx[e] = col  (8000 float4)
    for (int i = gtid; i < E * KT / 4; i += gs) {
        float4 v = tm[i];
        if (v.x != 0.f || v.y != 0.f || v.z != 0.f || v.w != 0.f) {
            float c[4] = {v.x, v.y, v.z, v.w};
#pragma unroll
            for (int k = 0; k < 4; k++)
                if (c[k] != 0.f) { int a = i * 4 + k; int e = a / KT; tidx[e] = a - e * KT; }
        }
    }
    // triple2r [NTRI,NRELS] (62500 float4): rels[j]
    for (int i = gtid; i < NTRI * NRELS / 4; i += gs) {
        float4 v = t2r[i];
        if (v.x != 0.f || v.y != 0.f || v.z != 0.f || v.w != 0.f) {
            float c[4] = {v.x, v.y, v.z, v.w};
#pragma unroll
            for (int k = 0; k < 4; k++)
                if (c[k] != 0.f) { int a = i * 4 + k; int j = a / NRELS; rels[j] = a - j * NRELS; }
        }
    }
    // e2triple [E,NTRI] -> heads ; triple2e [NTRI,E] -> tails (interleaved,
    // non-temporal: single-use streams, skip cache allocation).
    for (int i = gtid; i < E * NTRI / 4; i += gs) {
        f32x4 va = __builtin_nontemporal_load(&e2t[i]);
        f32x4 vb = __builtin_nontemporal_load(&t2e[i]);
        if (va.x != 0.f || va.y != 0.f || va.z != 0.f || va.w != 0.f) {
            float c[4] = {va.x, va.y, va.z, va.w};
#pragma unroll
            for (int k = 0; k < 4; k++)
                if (c[k] != 0.f) { int a = i * 4 + k; int hd = a / NTRI; heads[a - hd * NTRI] = hd; }
        }
        if (vb.x != 0.f || vb.y != 0.f || vb.z != 0.f || vb.w != 0.f) {
            float c[4] = {vb.x, vb.y, vb.z, vb.w};
#pragma unroll
            for (int k = 0; k < 4; k++)
                if (c[k] != 0.f) { int a = i * 4 + k; int j = a / E; tails[j] = a - j * E; }
        }
    }
}

// Kernel 2: build tail-rel bitmask + per-b head-matched triple lists ONCE.
// Replaces 256 redundant full-scan mask builds (~2.4M LDS atomics grid-wide)
// in the old mega_prop.
__global__ void __launch_bounds__(256) build_aux(
        const int* __restrict__ heads, const int* __restrict__ tails,
        const int* __restrict__ rels, const int* __restrict__ ent,
        unsigned int* __restrict__ mask_g, int* __restrict__ cnt_g,
        int* __restrict__ list_g) {
    int j = blockIdx.x * 256 + threadIdx.x;
    if (j >= NTRI) return;
    int r = rels[j];
    if (r < NRELS - 1) atomicOr(&mask_g[tails[j]], 1u << r);
    int hd = heads[j];
#pragma unroll
    for (int q = 0; q < B; q++) {
        if (hd == ent[q]) {
            int p = atomicAdd(&cnt_g[q], 1);
            if (p < LCAP) list_g[q * LCAP + p] = j;
        }
    }
}

// Kernel 3: one block per (b,l); all TT rounds internally, s stays in LDS.
// t=0 uses the ~5-entry head-matched list instead of a 10000-triple scan;
// mask/softmax come from precomputed global tables. t=2 fuses the
// l-reduction via global fp32 atomics into out.
__global__ void __launch_bounds__(512) mega_prop(
        const int* __restrict__ heads, const int* __restrict__ tails,
        const int* __restrict__ rels, const int* __restrict__ ent,
        const int* __restrict__ tidx,
        const unsigned int* __restrict__ mask_g, const int* __restrict__ cnt_g,
        const int* __restrict__ list_g, const float* __restrict__ wrow_g,
        const float* __restrict__ h, const float* __restrict__ h_type,
        const float* __restrict__ alpha, const float* __restrict__ beta,
        const float* __restrict__ h_x, const float* __restrict__ h_x_type,
        const float* __restrict__ alpha_x, const float* __restrict__ beta_x,
        const float* __restrict__ weight, float* __restrict__ out) {
    __shared__ float prev_s[E];
    __shared__ float acc_s[E];
    __shared__ unsigned int mask_s[E];
    __shared__ int tidx_s[E];
    __shared__ float wrow_s[NRELS];
    __shared__ float hp_s[NRELS - 1];
    __shared__ float htp_s[KT];
    __shared__ float extra_sh;

    const int NT = 512;
    const int bI = blockIdx.x >> 5, l = blockIdx.x & 31, tid = threadIdx.x;
    const int ent_b = ent[bI];
    const int cnt = min(cnt_g[bI], LCAP);

    for (int e = tid; e < E; e += NT) {
        acc_s[e] = 0.f;
        mask_s[e] = mask_g[e];
        tidx_s[e] = tidx[e];
    }

    const uint4* h4 = (const uint4*)heads;
    const uint4* t4 = (const uint4*)tails;
    const uint4* r4 = (const uint4*)rels;

    for (int t = 0; t < TT; t++) {
        const int tl = t * LL + l;
        if (tid < NRELS) wrow_s[tid] = wrow_g[tl * NRELS + tid];
        if (tid >= 64 && tid < 64 + NRELS - 1)
            hp_s[tid - 64] = clip01(h[tl * (NRELS - 1) + (tid - 64)] / TAU1);
        if (tid >= 128 && tid < 128 + KT)
            htp_s[tid - 128] = clip01(h_type[tl * KT + (tid - 128)] / TAU1);
        __syncthreads();

        if (t == 0) {
            for (int i = tid; i < cnt; i += NT) {
                int j = list_g[bI * LCAP + i];
                atomicAdd(&acc_s[tails[j]], wrow_s[rels[j]]);
            }
        } else {
            for (int i = tid; i < NTRI / 4; i += NT) {
                uint4 hh = h4[i];
                float p0 = prev_s[hh.x], p1 = prev_s[hh.y];
                float p2 = prev_s[hh.z], p3 = prev_s[hh.w];
                if (p0 != 0.f || p1 != 0.f || p2 != 0.f || p3 != 0.f) {
                    uint4 tv = t4[i], rr = r4[i];
                    if (p0 != 0.f) atomicAdd(&acc_s[tv.x], p0 * wrow_s[rr.x]);
                    if (p1 != 0.f) atomicAdd(&acc_s[tv.y], p1 * wrow_s[rr.y]);
                    if (p2 != 0.f) atomicAdd(&acc_s[tv.z], p2 * wrow_s[rr.z]);
                    if (p3 != 0.f) atomicAdd(&acc_s[tv.w], p3 * wrow_s[rr.w]);
                }
            }
        }
        __syncthreads();

        const float a = clip01(alpha[tl] / TAU1);
        const float bb = clip01(beta[tl] / TAU1);
        const float base = 1.f - clip01(a + bb);

        if (t == 0 && tid == 0) {
            unsigned int fl = 0u;
            for (int i = 0; i < cnt; i++) fl |= 1u << rels[list_g[bI * LCAP + i]];
            float hxlin = 0.f;
            for (int i = 0; i < NRELS - 1; i++) {
                int pi = (i < 12) ? (12 + i) : (i - 12);  // concat(hx_raw[:,12:24], hx_raw[:,0:12])
                if ((fl >> pi) & 1u) hxlin += clip01(h_x[l * (NRELS - 1) + i] / TAU1);
            }
            float htx = clip01(h_x_type[l * KT + tidx_s[ent_b]] / TAU1);
            float ax = clip01(alpha_x[l] / TAU1), bx = clip01(beta_x[l] / TAU1);
            extra_sh = clip01(a * htx + bb * hxlin) + (1.f - clip01(ax + bx));
        }
        __syncthreads();

        const float extra = (t == 0) ? extra_sh : 1.f;

        if (t < TT - 1) {
            for (int e = tid; e < E; e += NT) {
                unsigned int m = mask_s[e];
                float dot = 0.f;
#pragma unroll
                for (int i = 0; i < NRELS - 1; i++) dot += ((m >> i) & 1u) ? hp_s[i] : 0.f;
                float he = clip01(a * htp_s[tidx_s[e]] + bb * dot) + base;
                prev_s[e] = acc_s[e] * he * extra;
                acc_s[e] = 0.f;
            }
        } else {
            float tw = tanhf(weight[l]);
            for (int e = tid; e < E; e += NT) {
                unsigned int m = mask_s[e];
                float dot = 0.f;
#pragma unroll
                for (int i = 0; i < NRELS - 1; i++) dot += ((m >> i) & 1u) ? hp_s[i] : 0.f;
                float he = clip01(a * htp_s[tidx_s[e]] + bb * dot) + base;
                atomicAdd(&out[bI * E + e], acc_s[e] * he * tw);
            }
        }
        __syncthreads();
    }
}

extern "C" void kernel_launch(void* const* d_in, const int* in_sizes, int n_in,
                              void* d_out, int out_size, void* d_ws, size_t ws_size,
                              hipStream_t stream) {
    const float4* ix       = (const float4*)d_in[0];
    const float4* tm       = (const float4*)d_in[1];
    const f32x4*  e2t      = (const f32x4*)d_in[2];
    const f32x4*  t2e      = (const f32x4*)d_in[3];
    const float4* t2r      = (const float4*)d_in[4];
    const float*  w        = (const float*)d_in[5];
    const float*  weight   = (const float*)d_in[6];
    const float*  h        = (const float*)d_in[7];
    const float*  h_x      = (const float*)d_in[8];
    const float*  h_type   = (const float*)d_in[9];
    const float*  h_x_type = (const float*)d_in[10];
    const float*  alpha    = (const float*)d_in[11];
    const float*  beta     = (const float*)d_in[12];
    const float*  alpha_x  = (const float*)d_in[13];
    const float*  beta_x   = (const float*)d_in[14];
    (void)in_sizes; (void)n_in; (void)out_size; (void)ws_size;

    // All ws arrays are fully written before they are read (one-hot structure
    // => every slot has exactly one writer; mask/cnt zeroed in kernel 1;
    // stream ordering between dispatches orders the phases), so no memset
    // node is needed despite the 0xAA poison.
    char* ws = (char*)d_ws;
    int* heads = (int*)ws;                               // NTRI (padded 10048)
    int* tails = heads + 10048;                          // NTRI
    int* rels  = tails + 10048;                          // NTRI
    int* ent   = rels + 10048;                           // B   (padded 64)
    int* tidx  = ent + 64;                               // E   (padded 2048)
    unsigned int* mask_g = (unsigned int*)(tidx + 2048); // E   (padded 2048)
    int* cnt_g = (int*)(mask_g + 2048);                  // B   (padded 64)
    int* list_g = cnt_g + 64;                            // B*LCAP
    float* wrow_g = (float*)(list_g + B * LCAP);         // TT*LL*NRELS

    extract_all<<<XBLK, XTHR, 0, stream>>>(e2t, t2e, t2r, ix, tm, w,
                                           heads, tails, rels, ent, tidx,
                                           mask_g, cnt_g, wrow_g, (float4*)d_out);

    build_aux<<<(NTRI + 255) / 256, 256, 0, stream>>>(heads, tails, rels, ent,
                                                      mask_g, cnt_g, list_g);

    mega_prop<<<B * LL, 512, 0, stream>>>(heads, tails, rels, ent, tidx,
                                          mask_g, cnt_g, list_g, wrow_g,
                                          h, h_type, alpha, beta, h_x, h_x_type,
                                          alpha_x, beta_x, weight, (float*)d_out);
}